// Round 7
// baseline (388.135 us; speedup 1.0000x reference)
//
#include <hip/hip_runtime.h>
#include <hip/hip_bf16.h>

// B=2, L=2048, E=1024, H=16, D=64. Inputs fp32-or-bf16 (detected), mask int32.
// ws: flag@0 | mbits@64KB (1MB) | qp@2MB (8MB, reused for wfc_bf/bfc_bf after attn)
//     | kp@10MB | vpT@18MB | attn_out@26MB   (total 34MB)

#define B_ 2
#define L_ 2048
#define E_ 1024
#define H_ 16
#define D_ 64

typedef __attribute__((ext_vector_type(8))) short s8v;     // 8 bf16
typedef __attribute__((ext_vector_type(4))) float f4v;     // 4 fp32

__device__ __forceinline__ f4v mfma16(s8v a, s8v b, f4v c) {
    return __builtin_amdgcn_mfma_f32_16x16x32_bf16(a, b, c, 0, 0, 0);
}

__device__ __forceinline__ float fast_exp2(float x) {
    return __builtin_amdgcn_exp2f(x);
}

__device__ __forceinline__ ushort bf16bits(float f) {
    __hip_bfloat16 h = __float2bfloat16(f);
    return *(ushort*)&h;
}

// async global->LDS, 16B per lane; LDS dest = base + lane*16 (wave-uniform base)
__device__ __forceinline__ void glds16(const __hip_bfloat16* g, ushort* l) {
    __builtin_amdgcn_global_load_lds(
        (const __attribute__((address_space(1))) void*)g,
        (__attribute__((address_space(3))) void*)l,
        16, 0, 0);
}

__device__ __forceinline__ s8v ld8_dual(const void* p, size_t idx, bool isf32) {
    if (isf32) {
        const float* pf = (const float*)p + idx;
        f4v f0 = *(const f4v*)pf;
        f4v f1 = *(const f4v*)(pf + 4);
        s8v r;
        r[0] = (short)bf16bits(f0[0]); r[1] = (short)bf16bits(f0[1]);
        r[2] = (short)bf16bits(f0[2]); r[3] = (short)bf16bits(f0[3]);
        r[4] = (short)bf16bits(f1[0]); r[5] = (short)bf16bits(f1[1]);
        r[6] = (short)bf16bits(f1[2]); r[7] = (short)bf16bits(f1[3]);
        return r;
    }
    return *(const s8v*)((const __hip_bfloat16*)p + idx);
}

__device__ __forceinline__ s8v ld8_ws(const __hip_bfloat16* p) {
    return *(const s8v*)p;
}

// ---------------- dtype detection ----------------
__global__ void detect_kernel(const ushort* __restrict__ q, int* __restrict__ flag) {
    __shared__ int cnt;
    if (threadIdx.x == 0) cnt = 0;
    __syncthreads();
    int bad = 0;
    #pragma unroll
    for (int i = 0; i < 16; ++i) {
        ushort u = q[threadIdx.x * 16 + i];
        int e = (u >> 7) & 0xFF;
        if (e >= 0x8E) ++bad;
    }
    atomicAdd(&cnt, bad);
    __syncthreads();
    if (threadIdx.x == 0) *flag = (cnt > 100) ? 1 : 0;
}

// ---------------- mask -> bit pack ----------------
__global__ __launch_bounds__(256) void pack_mask_kernel(
    const int* __restrict__ mask, unsigned long long* __restrict__ mbits)
{
    const size_t widx = (size_t)blockIdx.x * 4 + (threadIdx.x >> 6);
    const int lane = threadIdx.x & 63;
    const int v = mask[widx * 64 + lane];
    const unsigned long long bal = __ballot(v != 0);
    if (lane == 0) mbits[widx] = bal;
}

// ---------------- Q/K projection -> [B,H,L,D] bf16 ----------------
__global__ __launch_bounds__(256) void qk_proj_kernel(
    const void* __restrict__ q_in, const void* __restrict__ k_in,
    const void* __restrict__ Wq,   const void* __restrict__ Wk,
    __hip_bfloat16* __restrict__ qp, __hip_bfloat16* __restrict__ kp,
    const int* __restrict__ flag)
{
    const bool isf32 = (*flag != 0);
    const int which = blockIdx.y;
    const void* X = which == 0 ? q_in : k_in;
    const void* W = which == 0 ? Wq : Wk;
    __hip_bfloat16* dst = which == 0 ? qp : kp;

    const int wave = threadIdx.x >> 6;
    const int lane = threadIdx.x & 63;
    const int quad = lane >> 4;
    const int l16  = lane & 15;
    const int m0 = (blockIdx.x * 4 + wave) * 16;

    const size_t abase = (size_t)(m0 + l16) * D_;
    s8v a0 = ld8_dual(X, abase + quad * 8, isf32);
    s8v a1 = ld8_dual(X, abase + 32 + quad * 8, isf32);

    f4v acc[4];
    #pragma unroll
    for (int nt = 0; nt < 4; ++nt) {
        const size_t bbase = (size_t)(nt * 16 + l16) * D_;
        s8v b0 = ld8_dual(W, bbase + quad * 8, isf32);
        s8v b1 = ld8_dual(W, bbase + 32 + quad * 8, isf32);
        f4v c = {0.f, 0.f, 0.f, 0.f};
        c = mfma16(a0, b0, c);
        c = mfma16(a1, b1, c);
        acc[nt] = c;
    }
    #pragma unroll
    for (int r = 0; r < 4; ++r) {
        const int m = m0 + quad * 4 + r;
        const int h = m & 15;
        const int bl = m >> 4;
        const int b = bl >> 11;
        const int l = bl & (L_ - 1);
        #pragma unroll
        for (int nt = 0; nt < 4; ++nt) {
            const int e = nt * 16 + l16;
            dst[(((size_t)(b * H_ + h)) * L_ + l) * D_ + e] = __float2bfloat16(acc[nt][r]);
        }
    }
}

// ---------------- V projection (transposed output [B,H,D,L]) ----------------
__global__ __launch_bounds__(256) void v_proj_kernel(
    const void* __restrict__ v_in, const void* __restrict__ Wv,
    __hip_bfloat16* __restrict__ vpT, const int* __restrict__ flag)
{
    const bool isf32 = (*flag != 0);
    __shared__ __align__(16) ushort tile[64][72];
    const int wave = threadIdx.x >> 6;
    const int lane = threadIdx.x & 63;
    const int quad = lane >> 4;
    const int l16  = lane & 15;
    const int l0 = blockIdx.x * 64;
    const int bh = blockIdx.y;
    const int b = bh >> 4, h = bh & 15;
    const int lw = l0 + wave * 16;

    const size_t xbase = ((size_t)(b * L_ + lw + l16)) * E_ + h * D_;
    s8v a0 = ld8_dual(v_in, xbase + quad * 8, isf32);
    s8v a1 = ld8_dual(v_in, xbase + 32 + quad * 8, isf32);

    #pragma unroll
    for (int nt = 0; nt < 4; ++nt) {
        const int e = nt * 16 + l16;
        s8v b0 = ld8_dual(Wv, (size_t)e * D_ + quad * 8, isf32);
        s8v b1 = ld8_dual(Wv, (size_t)e * D_ + 32 + quad * 8, isf32);
        f4v c = {0.f, 0.f, 0.f, 0.f};
        c = mfma16(a0, b0, c);
        c = mfma16(a1, b1, c);
        #pragma unroll
        for (int r = 0; r < 4; ++r)
            tile[wave * 16 + quad * 4 + r][e] = bf16bits(c[r]);
    }
    __syncthreads();
    const int e  = threadIdx.x >> 2;
    const int lc = (threadIdx.x & 3) * 16;
    s8v s0, s1;
    #pragma unroll
    for (int i = 0; i < 8; ++i) {
        s0[i] = (short)tile[lc + i][e];
        s1[i] = (short)tile[lc + 8 + i][e];
    }
    __hip_bfloat16* drow = vpT + ((size_t)bh * D_ + e) * L_ + l0 + lc;
    *(s8v*)drow = s0;
    *(s8v*)(drow + 8) = s1;
}

// ---------------- Flash attention, BK=64 ----------------
// K: LDS double-buffer via glds16, prefetch distance = one full iteration
// (the end-of-iter barrier drains a DMA issued a whole iteration earlier).
// V: direct global b128 register loads issued at iter top (vmcnt(2) wait
// leaves the K-DMA in flight). P: per-wave LDS + lgkm fence, no barrier.
__global__ __launch_bounds__(256, 4) void attn_kernel(
    const __hip_bfloat16* __restrict__ qp,
    const __hip_bfloat16* __restrict__ kp,
    const __hip_bfloat16* __restrict__ vpT,
    const unsigned long long* __restrict__ mbits,   // [B][L][32] u64
    __hip_bfloat16* __restrict__ attn_out)
{
    __shared__ __align__(16) ushort kbuf[2][64 * 64];   // 8KB x2, chunk-swizzled
    __shared__ __align__(16) ushort pbuf[4][16 * 76];   // per-wave P, stride 76

    const int wave = threadIdx.x >> 6;
    const int lane = threadIdx.x & 63;
    const int quad = lane >> 4;
    const int l16  = lane & 15;
    const int sw   = l16 & 7;                 // read-side swizzle key
    const int bh = blockIdx.y;
    const int b = bh >> 4, h = bh & 15;
    const int q0 = blockIdx.x * 64 + wave * 16;

    const float C2 = 0.045084439755930314f;   // log2(e)/32
    const float NEGBIG = -1.0e20f;

    const __hip_bfloat16* kbh = kp + (size_t)bh * L_ * D_;
    const __hip_bfloat16* vbh = vpT + (size_t)bh * D_ * L_;
    const unsigned long long* mrow_bits = mbits + (size_t)b * L_ * 32;

    // K staging geometry: one glds16 covers 8 rows (64 lanes x 16B = 1KB),
    // chunk-swizzled (lchk = (lane&7) ^ lrow) -> conflict-free frag reads.
    const int lrow = lane >> 3;
    const int lchk = (lane & 7) ^ (lrow & 7);
    const int r0 = wave * 16;                 // this wave stages rows r0..r0+15
    const __hip_bfloat16* kg0 = kbh + (size_t)(r0 + lrow) * D_ + lchk * 8;
    const __hip_bfloat16* kg1 = kbh + (size_t)(r0 + 8 + lrow) * D_ + lchk * 8;

    // Q fragments
    const __hip_bfloat16* qbase = qp + ((size_t)bh * L_ + q0) * D_;
    s8v qa0 = ld8_ws(qbase + (size_t)l16 * D_ + quad * 8);
    s8v qa1 = ld8_ws(qbase + (size_t)l16 * D_ + 32 + quad * 8);

    float m_i[4], li[4];
    #pragma unroll
    for (int r = 0; r < 4; ++r) { m_i[r] = -1.0e30f; li[r] = 0.f; }
    f4v o[4];
    #pragma unroll
    for (int nt = 0; nt < 4; ++nt) o[nt] = (f4v){0.f, 0.f, 0.f, 0.f};

    // preload K tile 0
    glds16(kg0, &kbuf[0][r0 * 64]);
    glds16(kg1, &kbuf[0][r0 * 64 + 512]);
    __syncthreads();

    int cur = 0;
    for (int it = 0; it < 32; ++it) {
        const int k0 = it * 64;
        // 1) mask bits (broadcast 8B loads)
        uint wlo[4], whi[4];
        #pragma unroll
        for (int r = 0; r < 4; ++r) {
            const unsigned long long wq = mrow_bits[(size_t)(q0 + quad * 4 + r) * 32 + it];
            wlo[r] = (uint)wq; whi[r] = (uint)(wq >> 32);
        }
        // 2) V fragments for THIS tile (consumed after softmax; vmcnt(2) wait)
        s8v vf0[4], vf1[4];
        #pragma unroll
        for (int nt = 0; nt < 4; ++nt) {
            const __hip_bfloat16* vrow = vbh + (size_t)(nt * 16 + l16) * L_ + k0;
            vf0[nt] = ld8_ws(vrow + quad * 8);
            vf1[nt] = ld8_ws(vrow + 32 + quad * 8);
        }
        // 3) K(it+1) DMA into the other buffer (drained at end-of-iter barrier)
        if (it < 31) {
            glds16(kg0 + (size_t)(k0 + 64) * D_, &kbuf[cur ^ 1][r0 * 64]);
            glds16(kg1 + (size_t)(k0 + 64) * D_, &kbuf[cur ^ 1][r0 * 64 + 512]);
        }
        // 4) S = Q K^T from kbuf[cur]
        f4v s[4];
        #pragma unroll
        for (int nt = 0; nt < 4; ++nt) {
            const ushort* kr = &kbuf[cur][(nt * 16 + l16) * 64];
            s8v kb0 = *(const s8v*)(kr + ((quad ^ sw) << 3));
            s8v kb1 = *(const s8v*)(kr + (((quad + 4) ^ sw) << 3));
            f4v c = {0.f, 0.f, 0.f, 0.f};
            c = mfma16(qa0, kb0, c);
            c = mfma16(qa1, kb1, c);
            s[nt] = c;
        }
        // mask BEFORE scale (reference order), exp2 domain
        #pragma unroll
        for (int nt = 0; nt < 4; ++nt) {
            const int sh = ((nt & 1) << 4) + l16;
            #pragma unroll
            for (int r = 0; r < 4; ++r) {
                const uint w = (nt & 2) ? whi[r] : wlo[r];
                const float sv = ((w >> sh) & 1u) ? s[nt][r] : NEGBIG;
                s[nt][r] = sv * C2;
            }
        }
        // online softmax
        #pragma unroll
        for (int r = 0; r < 4; ++r) {
            float v = fmaxf(fmaxf(s[0][r], s[1][r]), fmaxf(s[2][r], s[3][r]));
            #pragma unroll
            for (int off = 1; off < 16; off <<= 1)
                v = fmaxf(v, __shfl_xor(v, off, 64));
            const float mnew = fmaxf(m_i[r], v);
            const float alpha = fast_exp2(m_i[r] - mnew);
            m_i[r] = mnew;
            li[r] *= alpha;
            #pragma unroll
            for (int nt = 0; nt < 4; ++nt) o[nt][r] *= alpha;
        }
        float rsum[4] = {0.f, 0.f, 0.f, 0.f};
        #pragma unroll
        for (int nt = 0; nt < 4; ++nt) {
            #pragma unroll
            for (int r = 0; r < 4; ++r) {
                const float p = fast_exp2(s[nt][r] - m_i[r]);
                rsum[r] += p;
                pbuf[wave][(quad * 4 + r) * 76 + nt * 16 + l16] =
                    (ushort)((__float_as_uint(p) + 0x8000u) >> 16);
            }
        }
        #pragma unroll
        for (int r = 0; r < 4; ++r) {
            float v = rsum[r];
            #pragma unroll
            for (int off = 1; off < 16; off <<= 1)
                v += __shfl_xor(v, off, 64);
            li[r] += v;
        }
        // per-wave RAW fence for pbuf (DS in-order per wave; R5-verified)
        asm volatile("s_waitcnt lgkmcnt(0)" ::: "memory");
        const ushort* pw = &pbuf[wave][l16 * 76];
        s8v pa0 = *(const s8v*)(pw + quad * 8);
        s8v pa1 = *(const s8v*)(pw + 32 + quad * 8);
        // O += P @ V (V from registers)
        #pragma unroll
        for (int nt = 0; nt < 4; ++nt) {
            o[nt] = mfma16(pa0, vf0[nt], o[nt]);
            o[nt] = mfma16(pa1, vf1[nt], o[nt]);
        }
        // single barrier: kbuf[cur] reads done block-wide; K(it+1) DMA
        // (issued a full iteration ago) drains here.
        __syncthreads();
        cur ^= 1;
    }
    #pragma unroll
    for (int r = 0; r < 4; ++r) {
        const int row = q0 + quad * 4 + r;
        const float inv = 1.0f / li[r];
        #pragma unroll
        for (int nt = 0; nt < 4; ++nt) {
            const int d = nt * 16 + l16;
            attn_out[((size_t)(b * L_ + row)) * E_ + h * D_ + d] =
                __float2bfloat16(o[nt][r] * inv);
        }
    }
}

// ---------------- Wfc/bfc -> bf16 (into dead qp region) ----------------
__global__ __launch_bounds__(256) void cvt_wfc_kernel(
    const void* __restrict__ Wfc, const void* __restrict__ bfc,
    __hip_bfloat16* __restrict__ wfc_bf, __hip_bfloat16* __restrict__ bfc_bf,
    const int* __restrict__ flag)
{
    const bool isf32 = (*flag != 0);
    const size_t base = ((size_t)blockIdx.x * 256 + threadIdx.x) * 4;
    const size_t n1 = (size_t)E_ * E_;
    if (base >= n1 + E_) return;
    const void* src = (base < n1) ? Wfc : bfc;
    const size_t off = (base < n1) ? base : base - n1;
    __hip_bfloat16* dst = (base < n1) ? (wfc_bf + off) : (bfc_bf + off);
    if (isf32) {
        f4v v = *(const f4v*)((const float*)src + off);
        #pragma unroll
        for (int j = 0; j < 4; ++j) dst[j] = __float2bfloat16(v[j]);
    } else {
        *(ushort4*)dst = *(const ushort4*)((const ushort*)src + off);
    }
}

// ---------------- Output FC: out = x @ Wfc^T + bfc (register dbuf K-loop) ----------------
__global__ __launch_bounds__(256) void fc_kernel(
    const __hip_bfloat16* __restrict__ x,
    const __hip_bfloat16* __restrict__ wfc_bf,
    const __hip_bfloat16* __restrict__ bfc_bf,
    void* __restrict__ out, const int* __restrict__ flag)
{
    const bool isf32 = (*flag != 0);
    const int wave = threadIdx.x >> 6;
    const int lane = threadIdx.x & 63;
    const int quad = lane >> 4;
    const int l16  = lane & 15;
    const int m0 = blockIdx.x * 64 + wave * 16;
    const int n0 = blockIdx.y * 64;

    const __hip_bfloat16* xrow = x + (size_t)(m0 + l16) * E_;
    const __hip_bfloat16* wrow[4];
    #pragma unroll
    for (int nt = 0; nt < 4; ++nt)
        wrow[nt] = wfc_bf + (size_t)(n0 + nt * 16 + l16) * E_;

    f4v acc[4];
    #pragma unroll
    for (int nt = 0; nt < 4; ++nt) acc[nt] = (f4v){0.f, 0.f, 0.f, 0.f};

    // prefetch k0=0
    s8v a0 = ld8_ws(xrow + quad * 8);
    s8v a1 = ld8_ws(xrow + 32 + quad * 8);
    s8v b0[4], b1[4];
    #pragma unroll
    for (int nt = 0; nt < 4; ++nt) {
        b0[nt] = ld8_ws(wrow[nt] + quad * 8);
        b1[nt] = ld8_ws(wrow[nt] + 32 + quad * 8);
    }
    for (int k0 = 0; k0 < E_; k0 += 64) {
        s8v na0, na1, nb0[4], nb1[4];
        const int kn = k0 + 64;
        if (kn < E_) {
            na0 = ld8_ws(xrow + kn + quad * 8);
            na1 = ld8_ws(xrow + kn + 32 + quad * 8);
            #pragma unroll
            for (int nt = 0; nt < 4; ++nt) {
                nb0[nt] = ld8_ws(wrow[nt] + kn + quad * 8);
                nb1[nt] = ld8_ws(wrow[nt] + kn + 32 + quad * 8);
            }
        }
        #pragma unroll
        for (int nt = 0; nt < 4; ++nt) {
            acc[nt] = mfma16(a0, b0[nt], acc[nt]);
            acc[nt] = mfma16(a1, b1[nt], acc[nt]);
        }
        a0 = na0; a1 = na1;
        #pragma unroll
        for (int nt = 0; nt < 4; ++nt) { b0[nt] = nb0[nt]; b1[nt] = nb1[nt]; }
    }
    #pragma unroll
    for (int r = 0; r < 4; ++r) {
        const int m = m0 + quad * 4 + r;
        #pragma unroll
        for (int nt = 0; nt < 4; ++nt) {
            const int n = n0 + nt * 16 + l16;
            const float val = acc[nt][r] + __bfloat162float(bfc_bf[n]);
            if (isf32) ((float*)out)[(size_t)m * E_ + n] = val;
            else       ((__hip_bfloat16*)out)[(size_t)m * E_ + n] = __float2bfloat16(val);
        }
    }
}

extern "C" void kernel_launch(void* const* d_in, const int* in_sizes, int n_in,
                              void* d_out, int out_size, void* d_ws, size_t ws_size,
                              hipStream_t stream) {
    const void* query = d_in[0];
    const void* value = d_in[1];
    const void* key   = d_in[2];
    const int*  mask  = (const int*)d_in[3];
    const void* Wq  = d_in[4];
    const void* Wk  = d_in[5];
    const void* Wv  = d_in[6];
    const void* Wfc = d_in[7];
    const void* bfc = d_in[8];

    char* ws = (char*)d_ws;
    int* flag                     = (int*)ws;
    unsigned long long* mbits     = (unsigned long long*)(ws + (64u << 10));
    __hip_bfloat16* qp            = (__hip_bfloat16*)(ws + (2u  << 20));
    __hip_bfloat16* kp            = (__hip_bfloat16*)(ws + (10u << 20));
    __hip_bfloat16* vpT           = (__hip_bfloat16*)(ws + (18u << 20));
    __hip_bfloat16* attn_out      = (__hip_bfloat16*)(ws + (26u << 20));
    __hip_bfloat16* wfc_bf        = qp;                       // reused after attn
    __hip_bfloat16* bfc_bf        = qp + (size_t)E_ * E_;

    detect_kernel<<<1, 256, 0, stream>>>((const ushort*)query, flag);
    pack_mask_kernel<<<32768, 256, 0, stream>>>(mask, mbits);
    qk_proj_kernel<<<dim3(1024, 2), 256, 0, stream>>>(query, key, Wq, Wk, qp, kp, flag);
    v_proj_kernel<<<dim3(32, 32), 256, 0, stream>>>(value, Wv, vpT, flag);
    attn_kernel<<<dim3(32, 32), 256, 0, stream>>>(qp, kp, vpT, mbits, attn_out);
    cvt_wfc_kernel<<<1025, 256, 0, stream>>>(Wfc, bfc, wfc_bf, bfc_bf, flag);
    fc_kernel<<<dim3(64, 16), 256, 0, stream>>>(attn_out, wfc_bf, bfc_bf, d_out, flag);
}

// Round 8
// 358.583 us; speedup vs baseline: 1.0824x; 1.0824x over previous
//
#include <hip/hip_runtime.h>
#include <hip/hip_bf16.h>

// B=2, L=2048, E=1024, H=16, D=64. Inputs fp32-or-bf16 (detected), mask int32.
// ws: flag@0 | mbits@64KB (1MB) | qp@2MB | kp@10MB | vpT@18MB | attn_out@26MB (34MB total)

#define B_ 2
#define L_ 2048
#define E_ 1024
#define H_ 16
#define D_ 64

typedef __attribute__((ext_vector_type(8))) short s8v;     // 8 bf16
typedef __attribute__((ext_vector_type(4))) float f4v;     // 4 fp32

__device__ __forceinline__ f4v mfma16(s8v a, s8v b, f4v c) {
    return __builtin_amdgcn_mfma_f32_16x16x32_bf16(a, b, c, 0, 0, 0);
}

__device__ __forceinline__ float fast_exp2(float x) {
    return __builtin_amdgcn_exp2f(x);
}

__device__ __forceinline__ ushort bf16bits(float f) {
    __hip_bfloat16 h = __float2bfloat16(f);
    return *(ushort*)&h;
}

// async global->LDS, 16B/lane; LDS dest = wave-uniform base + lane*16
__device__ __forceinline__ void glds16(const __hip_bfloat16* g, ushort* l) {
    __builtin_amdgcn_global_load_lds(
        (const __attribute__((address_space(1))) void*)g,
        (__attribute__((address_space(3))) void*)l,
        16, 0, 0);
}

__device__ __forceinline__ s8v ld8_dual(const void* p, size_t idx, bool isf32) {
    if (isf32) {
        const float* pf = (const float*)p + idx;
        f4v f0 = *(const f4v*)pf;
        f4v f1 = *(const f4v*)(pf + 4);
        s8v r;
        r[0] = (short)bf16bits(f0[0]); r[1] = (short)bf16bits(f0[1]);
        r[2] = (short)bf16bits(f0[2]); r[3] = (short)bf16bits(f0[3]);
        r[4] = (short)bf16bits(f1[0]); r[5] = (short)bf16bits(f1[1]);
        r[6] = (short)bf16bits(f1[2]); r[7] = (short)bf16bits(f1[3]);
        return r;
    }
    return *(const s8v*)((const __hip_bfloat16*)p + idx);
}

__device__ __forceinline__ s8v ld8_ws(const __hip_bfloat16* p) {
    return *(const s8v*)p;
}

// ---------------- mask bit-pack + dtype detect (block 0) ----------------
__global__ __launch_bounds__(256) void pack_mask_kernel(
    const int* __restrict__ mask, unsigned long long* __restrict__ mbits,
    const ushort* __restrict__ q, int* __restrict__ flag)
{
    if (blockIdx.x == 0) {
        // fp32 reinterpreted as bf16 -> ~22% huge exponents; true bf16 N(0,1): none
        __shared__ int cnt;
        if (threadIdx.x == 0) cnt = 0;
        __syncthreads();
        int bad = 0;
        #pragma unroll
        for (int i = 0; i < 16; ++i) {
            ushort u = q[threadIdx.x * 16 + i];
            int e = (u >> 7) & 0xFF;
            if (e >= 0x8E) ++bad;
        }
        atomicAdd(&cnt, bad);
        __syncthreads();
        if (threadIdx.x == 0) *flag = (cnt > 100) ? 1 : 0;
    }
    const int wave = threadIdx.x >> 6;
    const int lane = threadIdx.x & 63;
    const size_t wbase = ((size_t)blockIdx.x * 4 + wave) * 4;
    #pragma unroll
    for (int i = 0; i < 4; ++i) {
        const size_t widx = wbase + i;
        const int v = mask[widx * 64 + lane];
        const unsigned long long bal = __ballot(v != 0);
        if (lane == 0) mbits[widx] = bal;
    }
}

// ---------------- merged Q/K/V projection ----------------
// grid (1024, 3): y=0 Q->qp[B,H,L,D], y=1 K->kp[B,H,L,D], y=2 V->vpT[B,H,D,L]
__global__ __launch_bounds__(256) void proj_all_kernel(
    const void* __restrict__ q_in, const void* __restrict__ k_in,
    const void* __restrict__ v_in,
    const void* __restrict__ Wq, const void* __restrict__ Wk,
    const void* __restrict__ Wv,
    __hip_bfloat16* __restrict__ qp, __hip_bfloat16* __restrict__ kp,
    __hip_bfloat16* __restrict__ vpT,
    const int* __restrict__ flag)
{
    __shared__ __align__(16) ushort tile[64][72];   // v-path transpose buffer
    const bool isf32 = (*flag != 0);
    const int wave = threadIdx.x >> 6;
    const int lane = threadIdx.x & 63;
    const int quad = lane >> 4;
    const int l16  = lane & 15;

    if (blockIdx.y < 2) {
        const void* X = blockIdx.y == 0 ? q_in : k_in;
        const void* W = blockIdx.y == 0 ? Wq : Wk;
        __hip_bfloat16* dst = blockIdx.y == 0 ? qp : kp;
        const int m0 = (blockIdx.x * 4 + wave) * 16;

        const size_t abase = (size_t)(m0 + l16) * D_;
        s8v a0 = ld8_dual(X, abase + quad * 8, isf32);
        s8v a1 = ld8_dual(X, abase + 32 + quad * 8, isf32);

        f4v acc[4];
        #pragma unroll
        for (int nt = 0; nt < 4; ++nt) {
            const size_t bbase = (size_t)(nt * 16 + l16) * D_;
            s8v b0 = ld8_dual(W, bbase + quad * 8, isf32);
            s8v b1 = ld8_dual(W, bbase + 32 + quad * 8, isf32);
            f4v c = {0.f, 0.f, 0.f, 0.f};
            c = mfma16(a0, b0, c);
            c = mfma16(a1, b1, c);
            acc[nt] = c;
        }
        #pragma unroll
        for (int r = 0; r < 4; ++r) {
            const int m = m0 + quad * 4 + r;
            const int h = m & 15;
            const int bl = m >> 4;
            const int b = bl >> 11;
            const int l = bl & (L_ - 1);
            #pragma unroll
            for (int nt = 0; nt < 4; ++nt) {
                const int e = nt * 16 + l16;
                dst[(((size_t)(b * H_ + h)) * L_ + l) * D_ + e] = __float2bfloat16(acc[nt][r]);
            }
        }
    } else {
        // V projection with LDS transpose -> vpT[B,H,D,L]
        const int l0 = (blockIdx.x & 31) * 64;
        const int bh = blockIdx.x >> 5;
        const int b = bh >> 4, h = bh & 15;
        const int lw = l0 + wave * 16;

        const size_t xbase = ((size_t)(b * L_ + lw + l16)) * E_ + h * D_;
        s8v a0 = ld8_dual(v_in, xbase + quad * 8, isf32);
        s8v a1 = ld8_dual(v_in, xbase + 32 + quad * 8, isf32);

        #pragma unroll
        for (int nt = 0; nt < 4; ++nt) {
            const int e = nt * 16 + l16;
            s8v b0 = ld8_dual(Wv, (size_t)e * D_ + quad * 8, isf32);
            s8v b1 = ld8_dual(Wv, (size_t)e * D_ + 32 + quad * 8, isf32);
            f4v c = {0.f, 0.f, 0.f, 0.f};
            c = mfma16(a0, b0, c);
            c = mfma16(a1, b1, c);
            #pragma unroll
            for (int r = 0; r < 4; ++r)
                tile[wave * 16 + quad * 4 + r][e] = bf16bits(c[r]);
        }
        __syncthreads();
        const int e  = threadIdx.x >> 2;
        const int lc = (threadIdx.x & 3) * 16;
        s8v s0, s1;
        #pragma unroll
        for (int i = 0; i < 8; ++i) {
            s0[i] = (short)tile[lc + i][e];
            s1[i] = (short)tile[lc + 8 + i][e];
        }
        __hip_bfloat16* drow = vpT + ((size_t)bh * D_ + e) * L_ + l0 + lc;
        *(s8v*)drow = s0;
        *(s8v*)(drow + 8) = s1;
    }
}

// ---------------- Flash attention, BK=64, no-max softmax ----------------
// Bounded scores (|S*log2e/32| < 1) make max-tracking numerically unnecessary:
// P = exp2(S*C2) in [~0.8,1.2]; masked -> exp2(-4.5e18) = 0 exactly.
// K,V double-buffered in LDS (deduped across waves) via glds16; one barrier/iter.
// Row-sum deferred: per-lane partials across all iters, one reduce in epilogue.
__global__ __launch_bounds__(256, 4) void attn_kernel(
    const __hip_bfloat16* __restrict__ qp,
    const __hip_bfloat16* __restrict__ kp,
    const __hip_bfloat16* __restrict__ vpT,
    const unsigned long long* __restrict__ mbits,   // [B][L][32] u64
    __hip_bfloat16* __restrict__ attn_out)
{
    __shared__ __align__(16) ushort kbuf[2][64 * 64];   // 8KB x2, chunk-swizzled
    __shared__ __align__(16) ushort vbuf[2][64 * 64];   // 8KB x2, chunk-swizzled
    __shared__ __align__(16) ushort pbuf[4][16 * 64];   // per-wave P, chunk-swizzled
    // total 40960 B -> exactly 4 blocks/CU (160 KiB)

    const int wave = threadIdx.x >> 6;
    const int lane = threadIdx.x & 63;
    const int quad = lane >> 4;
    const int l16  = lane & 15;
    const int sw   = l16 & 7;                 // read-side swizzle key
    const int bh = blockIdx.y;
    const int b = bh >> 4, h = bh & 15;
    const int q0 = blockIdx.x * 64 + wave * 16;

    const float C2 = 0.045084439755930314f;   // log2(e)/32
    const float NEGBIG = -1.0e20f;

    const __hip_bfloat16* kbh = kp + (size_t)bh * L_ * D_;
    const __hip_bfloat16* vbh = vpT + (size_t)bh * D_ * L_;
    const unsigned long long* mrow_bits = mbits + (size_t)b * L_ * 32;

    // staging geometry: one glds16 covers 8 rows (64 lanes x 16B), chunk-swizzled
    const int lrow = lane >> 3;
    const int lchk = (lane & 7) ^ lrow;
    const int r0 = wave * 16;                 // this wave stages rows r0..r0+15
    const __hip_bfloat16* kg0 = kbh + (size_t)(r0 + lrow) * D_ + lchk * 8;
    const __hip_bfloat16* kg1 = kbh + (size_t)(r0 + 8 + lrow) * D_ + lchk * 8;
    const __hip_bfloat16* vg0 = vbh + (size_t)(r0 + lrow) * L_ + lchk * 8;
    const __hip_bfloat16* vg1 = vbh + (size_t)(r0 + 8 + lrow) * L_ + lchk * 8;

    // Q fragments
    const __hip_bfloat16* qbase = qp + ((size_t)bh * L_ + q0) * D_;
    s8v qa0 = ld8_ws(qbase + (size_t)l16 * D_ + quad * 8);
    s8v qa1 = ld8_ws(qbase + (size_t)l16 * D_ + 32 + quad * 8);

    float rsum[4] = {0.f, 0.f, 0.f, 0.f};
    f4v o[4];
    #pragma unroll
    for (int nt = 0; nt < 4; ++nt) o[nt] = (f4v){0.f, 0.f, 0.f, 0.f};

    // preload tile 0 (K and V)
    glds16(kg0, &kbuf[0][r0 * 64]);
    glds16(kg1, &kbuf[0][r0 * 64 + 512]);
    glds16(vg0, &vbuf[0][r0 * 64]);
    glds16(vg1, &vbuf[0][r0 * 64 + 512]);
    __syncthreads();

    int cur = 0;
    for (int it = 0; it < 32; ++it) {
        const int k0 = it * 64;
        // mask bits (broadcast 8B loads)
        uint wlo[4], whi[4];
        #pragma unroll
        for (int r = 0; r < 4; ++r) {
            const unsigned long long wq = mrow_bits[(size_t)(q0 + quad * 4 + r) * 32 + it];
            wlo[r] = (uint)wq; whi[r] = (uint)(wq >> 32);
        }
        // prefetch K/V(it+1) into the other buffer; drained at end-of-iter barrier
        if (it < 31) {
            glds16(kg0 + (size_t)(k0 + 64) * D_, &kbuf[cur ^ 1][r0 * 64]);
            glds16(kg1 + (size_t)(k0 + 64) * D_, &kbuf[cur ^ 1][r0 * 64 + 512]);
            glds16(vg0 + (k0 + 64), &vbuf[cur ^ 1][r0 * 64]);
            glds16(vg1 + (k0 + 64), &vbuf[cur ^ 1][r0 * 64 + 512]);
        }
        // S = Q K^T from kbuf[cur]
        f4v s[4];
        #pragma unroll
        for (int nt = 0; nt < 4; ++nt) {
            const ushort* kr = &kbuf[cur][(nt * 16 + l16) * 64];
            s8v kb0 = *(const s8v*)(kr + ((quad ^ sw) << 3));
            s8v kb1 = *(const s8v*)(kr + (((quad + 4) ^ sw) << 3));
            f4v c = {0.f, 0.f, 0.f, 0.f};
            c = mfma16(qa0, kb0, c);
            c = mfma16(qa1, kb1, c);
            s[nt] = c;
        }
        // mask (before scale, reference order) -> exp2 -> accumulate -> pack to pbuf
        #pragma unroll
        for (int nt = 0; nt < 4; ++nt) {
            const int sh = ((nt & 1) << 4) + l16;
            const int chi = 2 * nt + (l16 >> 3);       // logical 8-col chunk
            #pragma unroll
            for (int r = 0; r < 4; ++r) {
                const uint w = (nt & 2) ? whi[r] : wlo[r];
                const float sv = ((w >> sh) & 1u) ? s[nt][r] : NEGBIG;
                const float p = fast_exp2(sv * C2);
                rsum[r] += p;
                const int row = quad * 4 + r;
                pbuf[wave][row * 64 + ((chi ^ (row & 7)) << 3) + (l16 & 7)] =
                    (ushort)((__float_as_uint(p) + 0x8000u) >> 16);
            }
        }
        // per-wave RAW fence for pbuf (DS in-order per wave)
        asm volatile("s_waitcnt lgkmcnt(0)" ::: "memory");
        const ushort* pw = &pbuf[wave][l16 * 64];
        s8v pa0 = *(const s8v*)(pw + ((quad ^ sw) << 3));
        s8v pa1 = *(const s8v*)(pw + (((quad + 4) ^ sw) << 3));
        // O += P @ V from vbuf[cur]
        #pragma unroll
        for (int nt = 0; nt < 4; ++nt) {
            const ushort* vr = &vbuf[cur][(nt * 16 + l16) * 64];
            s8v vb0 = *(const s8v*)(vr + ((quad ^ sw) << 3));
            s8v vb1 = *(const s8v*)(vr + (((quad + 4) ^ sw) << 3));
            o[nt] = mfma16(pa0, vb0, o[nt]);
            o[nt] = mfma16(pa1, vb1, o[nt]);
        }
        // single barrier: all reads of [cur] done block-wide; prefetch DMA drains
        __syncthreads();
        cur ^= 1;
    }
    // epilogue: reduce row sums (deferred across all iters), normalize, store
    #pragma unroll
    for (int r = 0; r < 4; ++r) {
        float v = rsum[r];
        #pragma unroll
        for (int off = 1; off < 16; off <<= 1)
            v += __shfl_xor(v, off, 64);
        const float inv = 1.0f / fmaxf(v, 1e-30f);
        const int row = q0 + quad * 4 + r;
        #pragma unroll
        for (int nt = 0; nt < 4; ++nt) {
            const int d = nt * 16 + l16;
            attn_out[((size_t)(b * L_ + row)) * E_ + h * D_ + d] =
                __float2bfloat16(o[nt][r] * inv);
        }
    }
}

// ---------------- Output FC: out = x @ Wfc^T + bfc (dual-dtype weights) ----------------
__global__ __launch_bounds__(256) void fc_kernel(
    const __hip_bfloat16* __restrict__ x,
    const void* __restrict__ Wfc, const void* __restrict__ bfc,
    void* __restrict__ out, const int* __restrict__ flag)
{
    const bool isf32 = (*flag != 0);
    const int wave = threadIdx.x >> 6;
    const int lane = threadIdx.x & 63;
    const int quad = lane >> 4;
    const int l16  = lane & 15;
    const int m0 = blockIdx.x * 64 + wave * 16;
    const int n0 = blockIdx.y * 64;

    f4v acc[4];
    #pragma unroll
    for (int nt = 0; nt < 4; ++nt) acc[nt] = (f4v){0.f, 0.f, 0.f, 0.f};

    for (int k0 = 0; k0 < E_; k0 += 32) {
        s8v a = ld8_ws(x + (size_t)(m0 + l16) * E_ + k0 + quad * 8);
        #pragma unroll
        for (int nt = 0; nt < 4; ++nt) {
            s8v bb = ld8_dual(Wfc, (size_t)(n0 + nt * 16 + l16) * E_ + k0 + quad * 8, isf32);
            acc[nt] = mfma16(a, bb, acc[nt]);
        }
    }
    #pragma unroll
    for (int r = 0; r < 4; ++r) {
        const int m = m0 + quad * 4 + r;
        #pragma unroll
        for (int nt = 0; nt < 4; ++nt) {
            const int n = n0 + nt * 16 + l16;
            const float bias = isf32 ? ((const float*)bfc)[n]
                                     : __bfloat162float(((const __hip_bfloat16*)bfc)[n]);
            const float val = acc[nt][r] + bias;
            if (isf32) ((float*)out)[(size_t)m * E_ + n] = val;
            else       ((__hip_bfloat16*)out)[(size_t)m * E_ + n] = __float2bfloat16(val);
        }
    }
}

extern "C" void kernel_launch(void* const* d_in, const int* in_sizes, int n_in,
                              void* d_out, int out_size, void* d_ws, size_t ws_size,
                              hipStream_t stream) {
    const void* query = d_in[0];
    const void* value = d_in[1];
    const void* key   = d_in[2];
    const int*  mask  = (const int*)d_in[3];
    const void* Wq  = d_in[4];
    const void* Wk  = d_in[5];
    const void* Wv  = d_in[6];
    const void* Wfc = d_in[7];
    const void* bfc = d_in[8];

    char* ws = (char*)d_ws;
    int* flag                     = (int*)ws;
    unsigned long long* mbits     = (unsigned long long*)(ws + (64u << 10));
    __hip_bfloat16* qp            = (__hip_bfloat16*)(ws + (2u  << 20));
    __hip_bfloat16* kp            = (__hip_bfloat16*)(ws + (10u << 20));
    __hip_bfloat16* vpT           = (__hip_bfloat16*)(ws + (18u << 20));
    __hip_bfloat16* attn_out      = (__hip_bfloat16*)(ws + (26u << 20));

    pack_mask_kernel<<<8192, 256, 0, stream>>>(mask, mbits, (const ushort*)query, flag);
    proj_all_kernel<<<dim3(1024, 3), 256, 0, stream>>>(
        query, key, value, Wq, Wk, Wv, qp, kp, vpT, flag);
    attn_kernel<<<dim3(32, 32), 256, 0, stream>>>(qp, kp, vpT, mbits, attn_out);
    fc_kernel<<<dim3(64, 16), 256, 0, stream>>>(attn_out, Wfc, bfc, d_out, flag);
}

// Round 9
// 244.040 us; speedup vs baseline: 1.5905x; 1.4694x over previous
//
#include <hip/hip_runtime.h>
#include <hip/hip_bf16.h>

// B=2, L=2048, E=1024, H=16, D=64. Inputs fp32-or-bf16 (detected), mask int32.
// ws: flag@0 | mbits@64KB (1MB) | qp@2MB | kp@10MB | vpT@18MB | attn_out@26MB
//     | wfc_bf@34MB (2MB+2KB, only if ws_size allows; else reuses qp after attn)

#define B_ 2
#define L_ 2048
#define E_ 1024
#define H_ 16
#define D_ 64

typedef __attribute__((ext_vector_type(8))) short s8v;     // 8 bf16
typedef __attribute__((ext_vector_type(4))) float f4v;     // 4 fp32

__device__ __forceinline__ f4v mfma16(s8v a, s8v b, f4v c) {
    return __builtin_amdgcn_mfma_f32_16x16x32_bf16(a, b, c, 0, 0, 0);
}

__device__ __forceinline__ float fast_exp2(float x) {
    return __builtin_amdgcn_exp2f(x);
}

__device__ __forceinline__ ushort bf16bits(float f) {
    __hip_bfloat16 h = __float2bfloat16(f);
    return *(ushort*)&h;
}

// async global->LDS, 16B/lane; LDS dest = wave-uniform base + lane*16
__device__ __forceinline__ void glds16(const __hip_bfloat16* g, ushort* l) {
    __builtin_amdgcn_global_load_lds(
        (const __attribute__((address_space(1))) void*)g,
        (__attribute__((address_space(3))) void*)l,
        16, 0, 0);
}

__device__ __forceinline__ s8v ld8_dual(const void* p, size_t idx, bool isf32) {
    if (isf32) {
        const float* pf = (const float*)p + idx;
        f4v f0 = *(const f4v*)pf;
        f4v f1 = *(const f4v*)(pf + 4);
        s8v r;
        r[0] = (short)bf16bits(f0[0]); r[1] = (short)bf16bits(f0[1]);
        r[2] = (short)bf16bits(f0[2]); r[3] = (short)bf16bits(f0[3]);
        r[4] = (short)bf16bits(f1[0]); r[5] = (short)bf16bits(f1[1]);
        r[6] = (short)bf16bits(f1[2]); r[7] = (short)bf16bits(f1[3]);
        return r;
    }
    return *(const s8v*)((const __hip_bfloat16*)p + idx);
}

__device__ __forceinline__ s8v ld8_ws(const __hip_bfloat16* p) {
    return *(const s8v*)p;
}

// convert 4 elements of Wfc/bfc (flat index i4*4) into bf16 staging buffers
__device__ __forceinline__ void cvt_piece(
    size_t i4, const void* Wfc, const void* bfc,
    __hip_bfloat16* wfc_bf, __hip_bfloat16* bfc_bf, bool isf32)
{
    const size_t base = i4 * 4;
    const size_t n1 = (size_t)E_ * E_;
    if (base >= n1 + E_) return;
    const void* src = (base < n1) ? Wfc : bfc;
    const size_t off = (base < n1) ? base : base - n1;
    __hip_bfloat16* dst = (base < n1) ? (wfc_bf + off) : (bfc_bf + off);
    if (isf32) {
        f4v v = *(const f4v*)((const float*)src + off);
        #pragma unroll
        for (int j = 0; j < 4; ++j) dst[j] = __float2bfloat16(v[j]);
    } else {
        *(ushort4*)dst = *(const ushort4*)((const ushort*)src + off);
    }
}

// ---------------- mask bit-pack + dtype detect (block 0) ----------------
__global__ __launch_bounds__(256) void pack_mask_kernel(
    const int* __restrict__ mask, unsigned long long* __restrict__ mbits,
    const ushort* __restrict__ q, int* __restrict__ flag)
{
    if (blockIdx.x == 0) {
        __shared__ int cnt;
        if (threadIdx.x == 0) cnt = 0;
        __syncthreads();
        int bad = 0;
        #pragma unroll
        for (int i = 0; i < 16; ++i) {
            ushort u = q[threadIdx.x * 16 + i];
            int e = (u >> 7) & 0xFF;
            if (e >= 0x8E) ++bad;
        }
        atomicAdd(&cnt, bad);
        __syncthreads();
        if (threadIdx.x == 0) *flag = (cnt > 100) ? 1 : 0;
    }
    const int wave = threadIdx.x >> 6;
    const int lane = threadIdx.x & 63;
    const size_t wbase = ((size_t)blockIdx.x * 4 + wave) * 4;
    #pragma unroll
    for (int i = 0; i < 4; ++i) {
        const size_t widx = wbase + i;
        const int v = mask[widx * 64 + lane];
        const unsigned long long bal = __ballot(v != 0);
        if (lane == 0) mbits[widx] = bal;
    }
}

// ---------------- merged Q/K/V projection (+ optional Wfc cvt slice) ----------------
// grid (1024, ny): y=0 Q->qp, y=1 K->kp, y=2 V->vpT, y=3 (if present) Wfc/bfc -> bf16
__global__ __launch_bounds__(256) void proj_all_kernel(
    const void* __restrict__ q_in, const void* __restrict__ k_in,
    const void* __restrict__ v_in,
    const void* __restrict__ Wq, const void* __restrict__ Wk,
    const void* __restrict__ Wv,
    const void* __restrict__ Wfc, const void* __restrict__ bfc,
    __hip_bfloat16* __restrict__ qp, __hip_bfloat16* __restrict__ kp,
    __hip_bfloat16* __restrict__ vpT,
    __hip_bfloat16* __restrict__ wfc_bf, __hip_bfloat16* __restrict__ bfc_bf,
    const int* __restrict__ flag)
{
    __shared__ __align__(16) ushort tile[64][72];   // v-path transpose buffer
    const bool isf32 = (*flag != 0);
    const int wave = threadIdx.x >> 6;
    const int lane = threadIdx.x & 63;
    const int quad = lane >> 4;
    const int l16  = lane & 15;

    if (blockIdx.y == 3) {
        cvt_piece((size_t)blockIdx.x * 256 + threadIdx.x, Wfc, bfc, wfc_bf, bfc_bf, isf32);
        if (blockIdx.x == 0)
            cvt_piece((size_t)(E_ * (size_t)E_ / 4) + threadIdx.x, Wfc, bfc, wfc_bf, bfc_bf, isf32);
        return;
    }
    if (blockIdx.y < 2) {
        const void* X = blockIdx.y == 0 ? q_in : k_in;
        const void* W = blockIdx.y == 0 ? Wq : Wk;
        __hip_bfloat16* dst = blockIdx.y == 0 ? qp : kp;
        const int m0 = (blockIdx.x * 4 + wave) * 16;

        const size_t abase = (size_t)(m0 + l16) * D_;
        s8v a0 = ld8_dual(X, abase + quad * 8, isf32);
        s8v a1 = ld8_dual(X, abase + 32 + quad * 8, isf32);

        f4v acc[4];
        #pragma unroll
        for (int nt = 0; nt < 4; ++nt) {
            const size_t bbase = (size_t)(nt * 16 + l16) * D_;
            s8v b0 = ld8_dual(W, bbase + quad * 8, isf32);
            s8v b1 = ld8_dual(W, bbase + 32 + quad * 8, isf32);
            f4v c = {0.f, 0.f, 0.f, 0.f};
            c = mfma16(a0, b0, c);
            c = mfma16(a1, b1, c);
            acc[nt] = c;
        }
        #pragma unroll
        for (int r = 0; r < 4; ++r) {
            const int m = m0 + quad * 4 + r;
            const int h = m & 15;
            const int bl = m >> 4;
            const int b = bl >> 11;
            const int l = bl & (L_ - 1);
            #pragma unroll
            for (int nt = 0; nt < 4; ++nt) {
                const int e = nt * 16 + l16;
                dst[(((size_t)(b * H_ + h)) * L_ + l) * D_ + e] = __float2bfloat16(acc[nt][r]);
            }
        }
    } else {
        // V projection with LDS transpose -> vpT[B,H,D,L]
        const int l0 = (blockIdx.x & 31) * 64;
        const int bh = blockIdx.x >> 5;
        const int b = bh >> 4, h = bh & 15;
        const int lw = l0 + wave * 16;

        const size_t xbase = ((size_t)(b * L_ + lw + l16)) * E_ + h * D_;
        s8v a0 = ld8_dual(v_in, xbase + quad * 8, isf32);
        s8v a1 = ld8_dual(v_in, xbase + 32 + quad * 8, isf32);

        #pragma unroll
        for (int nt = 0; nt < 4; ++nt) {
            const int e = nt * 16 + l16;
            s8v b0 = ld8_dual(Wv, (size_t)e * D_ + quad * 8, isf32);
            s8v b1 = ld8_dual(Wv, (size_t)e * D_ + 32 + quad * 8, isf32);
            f4v c = {0.f, 0.f, 0.f, 0.f};
            c = mfma16(a0, b0, c);
            c = mfma16(a1, b1, c);
            #pragma unroll
            for (int r = 0; r < 4; ++r)
                tile[wave * 16 + quad * 4 + r][e] = bf16bits(c[r]);
        }
        __syncthreads();
        const int e  = threadIdx.x >> 2;
        const int lc = (threadIdx.x & 3) * 16;
        s8v s0, s1;
        #pragma unroll
        for (int i = 0; i < 8; ++i) {
            s0[i] = (short)tile[lc + i][e];
            s1[i] = (short)tile[lc + 8 + i][e];
        }
        __hip_bfloat16* drow = vpT + ((size_t)bh * D_ + e) * L_ + l0 + lc;
        *(s8v*)drow = s0;
        *(s8v*)(drow + 8) = s1;
    }
}

// ---------------- standalone Wfc cvt (fallback when ws is tight; runs after attn) ----
__global__ __launch_bounds__(256) void cvt_wfc_kernel(
    const void* __restrict__ Wfc, const void* __restrict__ bfc,
    __hip_bfloat16* __restrict__ wfc_bf, __hip_bfloat16* __restrict__ bfc_bf,
    const int* __restrict__ flag)
{
    cvt_piece((size_t)blockIdx.x * 256 + threadIdx.x, Wfc, bfc, wfc_bf, bfc_bf, *flag != 0);
}

// ---------------- Flash attention, BK=64, no-max softmax (R8, unchanged) ----------------
__global__ __launch_bounds__(256, 4) void attn_kernel(
    const __hip_bfloat16* __restrict__ qp,
    const __hip_bfloat16* __restrict__ kp,
    const __hip_bfloat16* __restrict__ vpT,
    const unsigned long long* __restrict__ mbits,   // [B][L][32] u64
    __hip_bfloat16* __restrict__ attn_out)
{
    __shared__ __align__(16) ushort kbuf[2][64 * 64];
    __shared__ __align__(16) ushort vbuf[2][64 * 64];
    __shared__ __align__(16) ushort pbuf[4][16 * 64];

    const int wave = threadIdx.x >> 6;
    const int lane = threadIdx.x & 63;
    const int quad = lane >> 4;
    const int l16  = lane & 15;
    const int sw   = l16 & 7;
    const int bh = blockIdx.y;
    const int b = bh >> 4, h = bh & 15;
    const int q0 = blockIdx.x * 64 + wave * 16;

    const float C2 = 0.045084439755930314f;   // log2(e)/32
    const float NEGBIG = -1.0e20f;

    const __hip_bfloat16* kbh = kp + (size_t)bh * L_ * D_;
    const __hip_bfloat16* vbh = vpT + (size_t)bh * D_ * L_;
    const unsigned long long* mrow_bits = mbits + (size_t)b * L_ * 32;

    const int lrow = lane >> 3;
    const int lchk = (lane & 7) ^ lrow;
    const int r0 = wave * 16;
    const __hip_bfloat16* kg0 = kbh + (size_t)(r0 + lrow) * D_ + lchk * 8;
    const __hip_bfloat16* kg1 = kbh + (size_t)(r0 + 8 + lrow) * D_ + lchk * 8;
    const __hip_bfloat16* vg0 = vbh + (size_t)(r0 + lrow) * L_ + lchk * 8;
    const __hip_bfloat16* vg1 = vbh + (size_t)(r0 + 8 + lrow) * L_ + lchk * 8;

    const __hip_bfloat16* qbase = qp + ((size_t)bh * L_ + q0) * D_;
    s8v qa0 = ld8_ws(qbase + (size_t)l16 * D_ + quad * 8);
    s8v qa1 = ld8_ws(qbase + (size_t)l16 * D_ + 32 + quad * 8);

    float rsum[4] = {0.f, 0.f, 0.f, 0.f};
    f4v o[4];
    #pragma unroll
    for (int nt = 0; nt < 4; ++nt) o[nt] = (f4v){0.f, 0.f, 0.f, 0.f};

    glds16(kg0, &kbuf[0][r0 * 64]);
    glds16(kg1, &kbuf[0][r0 * 64 + 512]);
    glds16(vg0, &vbuf[0][r0 * 64]);
    glds16(vg1, &vbuf[0][r0 * 64 + 512]);
    __syncthreads();

    int cur = 0;
    for (int it = 0; it < 32; ++it) {
        const int k0 = it * 64;
        uint wlo[4], whi[4];
        #pragma unroll
        for (int r = 0; r < 4; ++r) {
            const unsigned long long wq = mrow_bits[(size_t)(q0 + quad * 4 + r) * 32 + it];
            wlo[r] = (uint)wq; whi[r] = (uint)(wq >> 32);
        }
        if (it < 31) {
            glds16(kg0 + (size_t)(k0 + 64) * D_, &kbuf[cur ^ 1][r0 * 64]);
            glds16(kg1 + (size_t)(k0 + 64) * D_, &kbuf[cur ^ 1][r0 * 64 + 512]);
            glds16(vg0 + (k0 + 64), &vbuf[cur ^ 1][r0 * 64]);
            glds16(vg1 + (k0 + 64), &vbuf[cur ^ 1][r0 * 64 + 512]);
        }
        f4v s[4];
        #pragma unroll
        for (int nt = 0; nt < 4; ++nt) {
            const ushort* kr = &kbuf[cur][(nt * 16 + l16) * 64];
            s8v kb0 = *(const s8v*)(kr + ((quad ^ sw) << 3));
            s8v kb1 = *(const s8v*)(kr + (((quad + 4) ^ sw) << 3));
            f4v c = {0.f, 0.f, 0.f, 0.f};
            c = mfma16(qa0, kb0, c);
            c = mfma16(qa1, kb1, c);
            s[nt] = c;
        }
        #pragma unroll
        for (int nt = 0; nt < 4; ++nt) {
            const int sh = ((nt & 1) << 4) + l16;
            const int chi = 2 * nt + (l16 >> 3);
            #pragma unroll
            for (int r = 0; r < 4; ++r) {
                const uint w = (nt & 2) ? whi[r] : wlo[r];
                const float sv = ((w >> sh) & 1u) ? s[nt][r] : NEGBIG;
                const float p = fast_exp2(sv * C2);
                rsum[r] += p;
                const int row = quad * 4 + r;
                pbuf[wave][row * 64 + ((chi ^ (row & 7)) << 3) + (l16 & 7)] =
                    (ushort)((__float_as_uint(p) + 0x8000u) >> 16);
            }
        }
        asm volatile("s_waitcnt lgkmcnt(0)" ::: "memory");
        const ushort* pw = &pbuf[wave][l16 * 64];
        s8v pa0 = *(const s8v*)(pw + ((quad ^ sw) << 3));
        s8v pa1 = *(const s8v*)(pw + (((quad + 4) ^ sw) << 3));
        #pragma unroll
        for (int nt = 0; nt < 4; ++nt) {
            const ushort* vr = &vbuf[cur][(nt * 16 + l16) * 64];
            s8v vb0 = *(const s8v*)(vr + ((quad ^ sw) << 3));
            s8v vb1 = *(const s8v*)(vr + (((quad + 4) ^ sw) << 3));
            o[nt] = mfma16(pa0, vb0, o[nt]);
            o[nt] = mfma16(pa1, vb1, o[nt]);
        }
        __syncthreads();
        cur ^= 1;
    }
    #pragma unroll
    for (int r = 0; r < 4; ++r) {
        float v = rsum[r];
        #pragma unroll
        for (int off = 1; off < 16; off <<= 1)
            v += __shfl_xor(v, off, 64);
        const float inv = 1.0f / fmaxf(v, 1e-30f);
        const int row = q0 + quad * 4 + r;
        #pragma unroll
        for (int nt = 0; nt < 4; ++nt) {
            const int d = nt * 16 + l16;
            attn_out[((size_t)(b * L_ + row)) * E_ + h * D_ + d] =
                __float2bfloat16(o[nt][r] * inv);
        }
    }
}

// ---------------- Output FC: LDS-staged dbuf GEMM (attn-pattern transplant) ----------------
// M=4096, N=1024, K=1024; 64x64 tiles; grid (64,16) = 1024 blocks = 4/CU.
__global__ __launch_bounds__(256, 4) void fc_kernel(
    const __hip_bfloat16* __restrict__ x,        // [4096, 1024] bf16
    const __hip_bfloat16* __restrict__ wfc_bf,   // [1024, 1024] bf16
    const __hip_bfloat16* __restrict__ bfc_bf,   // [1024] bf16
    void* __restrict__ out, const int* __restrict__ flag)
{
    __shared__ __align__(16) ushort abuf[2][64 * 64];   // 8KB x2
    __shared__ __align__(16) ushort bbuf[2][64 * 64];   // 8KB x2
    const bool isf32 = (*flag != 0);
    const int wave = threadIdx.x >> 6;
    const int lane = threadIdx.x & 63;
    const int quad = lane >> 4;
    const int l16  = lane & 15;
    const int sw   = l16 & 7;
    const int m0 = blockIdx.x * 64;
    const int n0 = blockIdx.y * 64;

    const int lrow = lane >> 3;
    const int lchk = (lane & 7) ^ lrow;
    const int r0 = wave * 16;
    const __hip_bfloat16* ag0 = x + (size_t)(m0 + r0 + lrow) * E_ + lchk * 8;
    const __hip_bfloat16* ag1 = x + (size_t)(m0 + r0 + 8 + lrow) * E_ + lchk * 8;
    const __hip_bfloat16* bg0 = wfc_bf + (size_t)(n0 + r0 + lrow) * E_ + lchk * 8;
    const __hip_bfloat16* bg1 = wfc_bf + (size_t)(n0 + r0 + 8 + lrow) * E_ + lchk * 8;

    f4v acc[4];
    #pragma unroll
    for (int nt = 0; nt < 4; ++nt) acc[nt] = (f4v){0.f, 0.f, 0.f, 0.f};

    glds16(ag0, &abuf[0][r0 * 64]);
    glds16(ag1, &abuf[0][r0 * 64 + 512]);
    glds16(bg0, &bbuf[0][r0 * 64]);
    glds16(bg1, &bbuf[0][r0 * 64 + 512]);
    __syncthreads();

    int cur = 0;
    for (int it = 0; it < 16; ++it) {
        const int k0 = it * 64;
        if (it < 15) {
            glds16(ag0 + k0 + 64, &abuf[cur ^ 1][r0 * 64]);
            glds16(ag1 + k0 + 64, &abuf[cur ^ 1][r0 * 64 + 512]);
            glds16(bg0 + k0 + 64, &bbuf[cur ^ 1][r0 * 64]);
            glds16(bg1 + k0 + 64, &bbuf[cur ^ 1][r0 * 64 + 512]);
        }
        const ushort* ar = &abuf[cur][(r0 + l16) * 64];
        s8v a0 = *(const s8v*)(ar + ((quad ^ sw) << 3));
        s8v a1 = *(const s8v*)(ar + (((quad + 4) ^ sw) << 3));
        #pragma unroll
        for (int nt = 0; nt < 4; ++nt) {
            const ushort* br = &bbuf[cur][(nt * 16 + l16) * 64];
            s8v b0 = *(const s8v*)(br + ((quad ^ sw) << 3));
            s8v b1 = *(const s8v*)(br + (((quad + 4) ^ sw) << 3));
            acc[nt] = mfma16(a0, b0, acc[nt]);
            acc[nt] = mfma16(a1, b1, acc[nt]);
        }
        __syncthreads();
        cur ^= 1;
    }
    #pragma unroll
    for (int r = 0; r < 4; ++r) {
        const int m = m0 + r0 + quad * 4 + r;
        #pragma unroll
        for (int nt = 0; nt < 4; ++nt) {
            const int n = n0 + nt * 16 + l16;
            const float val = acc[nt][r] + __bfloat162float(bfc_bf[n]);
            if (isf32) ((float*)out)[(size_t)m * E_ + n] = val;
            else       ((__hip_bfloat16*)out)[(size_t)m * E_ + n] = __float2bfloat16(val);
        }
    }
}

extern "C" void kernel_launch(void* const* d_in, const int* in_sizes, int n_in,
                              void* d_out, int out_size, void* d_ws, size_t ws_size,
                              hipStream_t stream) {
    const void* query = d_in[0];
    const void* value = d_in[1];
    const void* key   = d_in[2];
    const int*  mask  = (const int*)d_in[3];
    const void* Wq  = d_in[4];
    const void* Wk  = d_in[5];
    const void* Wv  = d_in[6];
    const void* Wfc = d_in[7];
    const void* bfc = d_in[8];

    char* ws = (char*)d_ws;
    int* flag                     = (int*)ws;
    unsigned long long* mbits     = (unsigned long long*)(ws + (64u << 10));
    __hip_bfloat16* qp            = (__hip_bfloat16*)(ws + (2u  << 20));
    __hip_bfloat16* kp            = (__hip_bfloat16*)(ws + (10u << 20));
    __hip_bfloat16* vpT           = (__hip_bfloat16*)(ws + (18u << 20));
    __hip_bfloat16* attn_out      = (__hip_bfloat16*)(ws + (26u << 20));

    // Weight staging: dedicated region if ws allows (cvt fused into proj);
    // else reuse qp after attn via a separate cvt launch. Branch is on a
    // launch-constant (ws_size) -> identical work every call, graph-safe.
    const bool big_ws = ws_size >= (37ull << 20);
    __hip_bfloat16* wfc_bf = big_ws ? (__hip_bfloat16*)(ws + (34ull << 20)) : qp;
    __hip_bfloat16* bfc_bf = wfc_bf + (size_t)E_ * E_;

    pack_mask_kernel<<<8192, 256, 0, stream>>>(mask, mbits, (const ushort*)query, flag);
    proj_all_kernel<<<dim3(1024, big_ws ? 4 : 3), 256, 0, stream>>>(
        query, key, value, Wq, Wk, Wv, Wfc, bfc, qp, kp, vpT, wfc_bf, bfc_bf, flag);
    attn_kernel<<<dim3(32, 32), 256, 0, stream>>>(qp, kp, vpT, mbits, attn_out);
    if (!big_ws)
        cvt_wfc_kernel<<<1025, 256, 0, stream>>>(Wfc, bfc, wfc_bf, bfc_bf, flag);
    fc_kernel<<<dim3(64, 16), 256, 0, stream>>>(attn_out, wfc_bf, bfc_bf, d_out, flag);
}

// Round 10
// 241.716 us; speedup vs baseline: 1.6057x; 1.0096x over previous
//
#include <hip/hip_runtime.h>
#include <hip/hip_bf16.h>

// B=2, L=2048, E=1024, H=16, D=64. Inputs fp32-or-bf16 (detected), mask int32.
// ws: flag@0 | mbits@64KB (1MB) | qp@2MB | kp@10MB | vpT@18MB | attn_out@26MB
//     | wfc_bf@34MB (if ws allows; else reuses qp after attn)
// qp holds Q pre-scaled by log2(e)/32 (fold of mask-then-scale semantics).

#define B_ 2
#define L_ 2048
#define E_ 1024
#define H_ 16
#define D_ 64

typedef __attribute__((ext_vector_type(8))) short s8v;     // 8 bf16
typedef __attribute__((ext_vector_type(4))) float f4v;     // 4 fp32

__device__ __forceinline__ f4v mfma16(s8v a, s8v b, f4v c) {
    return __builtin_amdgcn_mfma_f32_16x16x32_bf16(a, b, c, 0, 0, 0);
}

__device__ __forceinline__ float fast_exp2(float x) {
    return __builtin_amdgcn_exp2f(x);
}

__device__ __forceinline__ ushort bf16bits(float f) {
    __hip_bfloat16 h = __float2bfloat16(f);
    return *(ushort*)&h;
}

// async global->LDS, 16B/lane; LDS dest = wave-uniform base + lane*16
__device__ __forceinline__ void glds16(const __hip_bfloat16* g, ushort* l) {
    __builtin_amdgcn_global_load_lds(
        (const __attribute__((address_space(1))) void*)g,
        (__attribute__((address_space(3))) void*)l,
        16, 0, 0);
}

__device__ __forceinline__ s8v ld8_dual(const void* p, size_t idx, bool isf32) {
    if (isf32) {
        const float* pf = (const float*)p + idx;
        f4v f0 = *(const f4v*)pf;
        f4v f1 = *(const f4v*)(pf + 4);
        s8v r;
        r[0] = (short)bf16bits(f0[0]); r[1] = (short)bf16bits(f0[1]);
        r[2] = (short)bf16bits(f0[2]); r[3] = (short)bf16bits(f0[3]);
        r[4] = (short)bf16bits(f1[0]); r[5] = (short)bf16bits(f1[1]);
        r[6] = (short)bf16bits(f1[2]); r[7] = (short)bf16bits(f1[3]);
        return r;
    }
    return *(const s8v*)((const __hip_bfloat16*)p + idx);
}

__device__ __forceinline__ s8v ld8_ws(const __hip_bfloat16* p) {
    return *(const s8v*)p;
}

// convert 4 elements of Wfc/bfc (flat index i4*4) into bf16 staging buffers
__device__ __forceinline__ void cvt_piece(
    size_t i4, const void* Wfc, const void* bfc,
    __hip_bfloat16* wfc_bf, __hip_bfloat16* bfc_bf, bool isf32)
{
    const size_t base = i4 * 4;
    const size_t n1 = (size_t)E_ * E_;
    if (base >= n1 + E_) return;
    const void* src = (base < n1) ? Wfc : bfc;
    const size_t off = (base < n1) ? base : base - n1;
    __hip_bfloat16* dst = (base < n1) ? (wfc_bf + off) : (bfc_bf + off);
    if (isf32) {
        f4v v = *(const f4v*)((const float*)src + off);
        #pragma unroll
        for (int j = 0; j < 4; ++j) dst[j] = __float2bfloat16(v[j]);
    } else {
        *(ushort4*)dst = *(const ushort4*)((const ushort*)src + off);
    }
}

// ---------------- dtype detect (must precede proj: it reads *flag) ----------------
__global__ void detect_kernel(const ushort* __restrict__ q, int* __restrict__ flag) {
    __shared__ int cnt;
    if (threadIdx.x == 0) cnt = 0;
    __syncthreads();
    int bad = 0;
    #pragma unroll
    for (int i = 0; i < 16; ++i) {
        ushort u = q[threadIdx.x * 16 + i];
        int e = (u >> 7) & 0xFF;
        if (e >= 0x8E) ++bad;
    }
    atomicAdd(&cnt, bad);
    __syncthreads();
    if (threadIdx.x == 0) *flag = (cnt > 100) ? 1 : 0;
}

// ---------------- merged Q/K/V projection + mask pack (+ optional Wfc cvt) --------
// grid (1024, ny): y=0 Q(prescaled)->qp, y=1 K->kp, y=2 V->vpT,
//                  y=3 mask bit-pack, y=4 (if present) Wfc/bfc -> bf16
__global__ __launch_bounds__(256) void proj_all_kernel(
    const void* __restrict__ q_in, const void* __restrict__ k_in,
    const void* __restrict__ v_in,
    const void* __restrict__ Wq, const void* __restrict__ Wk,
    const void* __restrict__ Wv,
    const void* __restrict__ Wfc, const void* __restrict__ bfc,
    const int* __restrict__ mask, unsigned long long* __restrict__ mbits,
    __hip_bfloat16* __restrict__ qp, __hip_bfloat16* __restrict__ kp,
    __hip_bfloat16* __restrict__ vpT,
    __hip_bfloat16* __restrict__ wfc_bf, __hip_bfloat16* __restrict__ bfc_bf,
    const int* __restrict__ flag)
{
    __shared__ __align__(16) ushort tile[64][72];   // v-path transpose buffer
    const bool isf32 = (*flag != 0);
    const int wave = threadIdx.x >> 6;
    const int lane = threadIdx.x & 63;
    const int quad = lane >> 4;
    const int l16  = lane & 15;

    if (blockIdx.y == 3) {
        // mask -> ballot bits: 128 u64 per block (32 per wave)
        const int lane_ = threadIdx.x & 63;
        const size_t wbase = (size_t)blockIdx.x * 128 + wave * 32;
        #pragma unroll 4
        for (int i = 0; i < 32; ++i) {
            const size_t widx = wbase + i;
            const int v = mask[widx * 64 + lane_];
            const unsigned long long bal = __ballot(v != 0);
            if (lane_ == 0) mbits[widx] = bal;
        }
        return;
    }
    if (blockIdx.y == 4) {
        cvt_piece((size_t)blockIdx.x * 256 + threadIdx.x, Wfc, bfc, wfc_bf, bfc_bf, isf32);
        if (blockIdx.x == 0)
            cvt_piece((size_t)(E_ * (size_t)E_ / 4) + threadIdx.x, Wfc, bfc, wfc_bf, bfc_bf, isf32);
        return;
    }
    if (blockIdx.y < 2) {
        const void* X = blockIdx.y == 0 ? q_in : k_in;
        const void* W = blockIdx.y == 0 ? Wq : Wk;
        __hip_bfloat16* dst = blockIdx.y == 0 ? qp : kp;
        // fold softmax scale (log2e/32) into Q
        const float oscale = (blockIdx.y == 0) ? 0.045084439755930314f : 1.0f;
        const int m0 = (blockIdx.x * 4 + wave) * 16;

        const size_t abase = (size_t)(m0 + l16) * D_;
        s8v a0 = ld8_dual(X, abase + quad * 8, isf32);
        s8v a1 = ld8_dual(X, abase + 32 + quad * 8, isf32);

        f4v acc[4];
        #pragma unroll
        for (int nt = 0; nt < 4; ++nt) {
            const size_t bbase = (size_t)(nt * 16 + l16) * D_;
            s8v b0 = ld8_dual(W, bbase + quad * 8, isf32);
            s8v b1 = ld8_dual(W, bbase + 32 + quad * 8, isf32);
            f4v c = {0.f, 0.f, 0.f, 0.f};
            c = mfma16(a0, b0, c);
            c = mfma16(a1, b1, c);
            acc[nt] = c;
        }
        #pragma unroll
        for (int r = 0; r < 4; ++r) {
            const int m = m0 + quad * 4 + r;
            const int h = m & 15;
            const int bl = m >> 4;
            const int b = bl >> 11;
            const int l = bl & (L_ - 1);
            #pragma unroll
            for (int nt = 0; nt < 4; ++nt) {
                const int e = nt * 16 + l16;
                dst[(((size_t)(b * H_ + h)) * L_ + l) * D_ + e] =
                    __float2bfloat16(acc[nt][r] * oscale);
            }
        }
    } else {
        // V projection with LDS transpose -> vpT[B,H,D,L]
        const int l0 = (blockIdx.x & 31) * 64;
        const int bh = blockIdx.x >> 5;
        const int b = bh >> 4, h = bh & 15;
        const int lw = l0 + wave * 16;

        const size_t xbase = ((size_t)(b * L_ + lw + l16)) * E_ + h * D_;
        s8v a0 = ld8_dual(v_in, xbase + quad * 8, isf32);
        s8v a1 = ld8_dual(v_in, xbase + 32 + quad * 8, isf32);

        #pragma unroll
        for (int nt = 0; nt < 4; ++nt) {
            const int e = nt * 16 + l16;
            s8v b0 = ld8_dual(Wv, (size_t)e * D_ + quad * 8, isf32);
            s8v b1 = ld8_dual(Wv, (size_t)e * D_ + 32 + quad * 8, isf32);
            f4v c = {0.f, 0.f, 0.f, 0.f};
            c = mfma16(a0, b0, c);
            c = mfma16(a1, b1, c);
            #pragma unroll
            for (int r = 0; r < 4; ++r)
                tile[wave * 16 + quad * 4 + r][e] = bf16bits(c[r]);
        }
        __syncthreads();
        const int e  = threadIdx.x >> 2;
        const int lc = (threadIdx.x & 3) * 16;
        s8v s0, s1;
        #pragma unroll
        for (int i = 0; i < 8; ++i) {
            s0[i] = (short)tile[lc + i][e];
            s1[i] = (short)tile[lc + 8 + i][e];
        }
        __hip_bfloat16* drow = vpT + ((size_t)bh * D_ + e) * L_ + l0 + lc;
        *(s8v*)drow = s0;
        *(s8v*)(drow + 8) = s1;
    }
}

// ---------------- standalone Wfc cvt (fallback when ws is tight; after attn) ------
__global__ __launch_bounds__(256) void cvt_wfc_kernel(
    const void* __restrict__ Wfc, const void* __restrict__ bfc,
    __hip_bfloat16* __restrict__ wfc_bf, __hip_bfloat16* __restrict__ bfc_bf,
    const int* __restrict__ flag)
{
    cvt_piece((size_t)blockIdx.x * 256 + threadIdx.x, Wfc, bfc, wfc_bf, bfc_bf, *flag != 0);
}

// ---------------- Flash attention, BK=64, S^T orientation, no-max softmax ---------
// S^T = K·Q^T (swapped mfma operands): col=lane&15 = q, row=quad*4+r = k.
// -> ONE mask u64 per lane per iter (its own q-row); bit = nt*16+quad*4+r.
// Q pre-scaled by log2e/32 in proj; masked = exp2(-4.5e18) = 0 exactly.
// P pairs packed -> 4 ds_write_b64/iter (k-consecutive slots), XOR-chunk swizzle.
// rsum: per-lane scalar across all iters; quad-reduce + redistribute in epilogue.
__global__ __launch_bounds__(256, 4) void attn_kernel(
    const __hip_bfloat16* __restrict__ qp,
    const __hip_bfloat16* __restrict__ kp,
    const __hip_bfloat16* __restrict__ vpT,
    const unsigned long long* __restrict__ mbits,   // [B][L][32] u64
    __hip_bfloat16* __restrict__ attn_out)
{
    __shared__ __align__(16) ushort kbuf[2][64 * 64];
    __shared__ __align__(16) ushort vbuf[2][64 * 64];
    __shared__ __align__(16) ushort pbuf[4][16 * 64];

    const int wave = threadIdx.x >> 6;
    const int lane = threadIdx.x & 63;
    const int quad = lane >> 4;
    const int l16  = lane & 15;
    const int sw   = l16 & 7;
    const int bh = blockIdx.y;
    const int b = bh >> 4, h = bh & 15;
    const int q0 = blockIdx.x * 64 + wave * 16;

    const uint NEGB = __float_as_uint(-4.5084439e18f);   // (-1e20)*log2e/32

    const __hip_bfloat16* kbh = kp + (size_t)bh * L_ * D_;
    const __hip_bfloat16* vbh = vpT + (size_t)bh * D_ * L_;
    // one u64 of mask bits per lane per iter: row = q0 + l16
    const unsigned long long* mrow = mbits + ((size_t)b * L_ + q0 + l16) * 32;

    const int lrow = lane >> 3;
    const int lchk = (lane & 7) ^ lrow;
    const int r0 = wave * 16;
    const __hip_bfloat16* kg0 = kbh + (size_t)(r0 + lrow) * D_ + lchk * 8;
    const __hip_bfloat16* kg1 = kbh + (size_t)(r0 + 8 + lrow) * D_ + lchk * 8;
    const __hip_bfloat16* vg0 = vbh + (size_t)(r0 + lrow) * L_ + lchk * 8;
    const __hip_bfloat16* vg1 = vbh + (size_t)(r0 + 8 + lrow) * L_ + lchk * 8;

    const __hip_bfloat16* qbase = qp + ((size_t)bh * L_ + q0) * D_;
    s8v qa0 = ld8_ws(qbase + (size_t)l16 * D_ + quad * 8);
    s8v qa1 = ld8_ws(qbase + (size_t)l16 * D_ + 32 + quad * 8);

    float rsum = 0.f;
    f4v o[4];
    #pragma unroll
    for (int nt = 0; nt < 4; ++nt) o[nt] = (f4v){0.f, 0.f, 0.f, 0.f};

    // P-store pointers (iteration-invariant): chunk c = nt*2 + (quad>>1),
    // slot base = 4*(quad&1); addr = l16*64 + ((c^sw)<<3) + slotbase (8B-aligned)
    uint2* pdst[4];
    #pragma unroll
    for (int nt = 0; nt < 4; ++nt) {
        const int c = nt * 2 + (quad >> 1);
        pdst[nt] = (uint2*)&pbuf[wave][l16 * 64 + ((c ^ sw) << 3) + 4 * (quad & 1)];
    }

    glds16(kg0, &kbuf[0][r0 * 64]);
    glds16(kg1, &kbuf[0][r0 * 64 + 512]);
    glds16(vg0, &vbuf[0][r0 * 64]);
    glds16(vg1, &vbuf[0][r0 * 64 + 512]);
    __syncthreads();

    int cur = 0;
    for (int it = 0; it < 32; ++it) {
        const int k0 = it * 64;
        const unsigned long long wq = mrow[it];
        const uint wlo = (uint)wq, whi = (uint)(wq >> 32);
        if (it < 31) {
            glds16(kg0 + (size_t)(k0 + 64) * D_, &kbuf[cur ^ 1][r0 * 64]);
            glds16(kg1 + (size_t)(k0 + 64) * D_, &kbuf[cur ^ 1][r0 * 64 + 512]);
            glds16(vg0 + (k0 + 64), &vbuf[cur ^ 1][r0 * 64]);
            glds16(vg1 + (k0 + 64), &vbuf[cur ^ 1][r0 * 64 + 512]);
        }
        // S^T = K·Q^T: tile nt = k-rows [nt*16, nt*16+16) x q-cols (l16)
        f4v s[4];
        #pragma unroll
        for (int nt = 0; nt < 4; ++nt) {
            const ushort* kr = &kbuf[cur][(nt * 16 + l16) * 64];
            s8v kb0 = *(const s8v*)(kr + ((quad ^ sw) << 3));
            s8v kb1 = *(const s8v*)(kr + (((quad + 4) ^ sw) << 3));
            f4v c = {0.f, 0.f, 0.f, 0.f};
            c = mfma16(kb0, qa0, c);
            c = mfma16(kb1, qa1, c);
            s[nt] = c;
        }
        // mask (bfi select) -> exp2 -> rsum -> pack pairs -> b64 store
        #pragma unroll
        for (int nt = 0; nt < 4; ++nt) {
            const uint w = (nt & 2) ? whi : wlo;
            float pr[4];
            #pragma unroll
            for (int r = 0; r < 4; ++r) {
                const int idx = ((nt & 1) << 4) + quad * 4 + r;     // bit in w
                const uint m = (uint)(((int)(w << (31 - idx))) >> 31);
                const uint sb = (__float_as_uint(s[nt][r]) & m) | (NEGB & ~m);
                const float p = fast_exp2(__uint_as_float(sb));
                rsum += p;
                pr[r] = p;
            }
            const uint dw0 = ((__float_as_uint(pr[0]) + 0x8000u) >> 16) |
                             ((__float_as_uint(pr[1]) + 0x8000u) & 0xFFFF0000u);
            const uint dw1 = ((__float_as_uint(pr[2]) + 0x8000u) >> 16) |
                             ((__float_as_uint(pr[3]) + 0x8000u) & 0xFFFF0000u);
            *pdst[nt] = make_uint2(dw0, dw1);
        }
        // per-wave RAW fence for pbuf (DS in-order per wave)
        asm volatile("s_waitcnt lgkmcnt(0)" ::: "memory");
        const ushort* pw = &pbuf[wave][l16 * 64];
        s8v pa0 = *(const s8v*)(pw + ((quad ^ sw) << 3));
        s8v pa1 = *(const s8v*)(pw + (((quad + 4) ^ sw) << 3));
        // O += P·V from vbuf[cur]  (C: row=q=quad*4+r, col=d=nt*16+l16)
        #pragma unroll
        for (int nt = 0; nt < 4; ++nt) {
            const ushort* vr = &vbuf[cur][(nt * 16 + l16) * 64];
            s8v vb0 = *(const s8v*)(vr + ((quad ^ sw) << 3));
            s8v vb1 = *(const s8v*)(vr + (((quad + 4) ^ sw) << 3));
            o[nt] = mfma16(pa0, vb0, o[nt]);
            o[nt] = mfma16(pa1, vb1, o[nt]);
        }
        __syncthreads();
        cur ^= 1;
    }
    // epilogue: rsum lives per (quad, q=l16) -> reduce across quads, redistribute
    float v = rsum;
    v += __shfl_xor(v, 16, 64);
    v += __shfl_xor(v, 32, 64);       // now every lane holds sum for q = its l16
    #pragma unroll
    for (int r = 0; r < 4; ++r) {
        const int qrow = quad * 4 + r;                       // O-row within wave
        const float li = __shfl(v, qrow, 64);                // from lane with l16==qrow
        const float inv = 1.0f / fmaxf(li, 1e-30f);
        const int row = q0 + qrow;
        #pragma unroll
        for (int nt = 0; nt < 4; ++nt) {
            const int d = nt * 16 + l16;
            attn_out[((size_t)(b * L_ + row)) * E_ + h * D_ + d] =
                __float2bfloat16(o[nt][r] * inv);
        }
    }
}

// ---------------- Output FC: LDS-staged dbuf GEMM (R9, unchanged) ----------------
__global__ __launch_bounds__(256, 4) void fc_kernel(
    const __hip_bfloat16* __restrict__ x,
    const __hip_bfloat16* __restrict__ wfc_bf,
    const __hip_bfloat16* __restrict__ bfc_bf,
    void* __restrict__ out, const int* __restrict__ flag)
{
    __shared__ __align__(16) ushort abuf[2][64 * 64];
    __shared__ __align__(16) ushort bbuf[2][64 * 64];
    const bool isf32 = (*flag != 0);
    const int wave = threadIdx.x >> 6;
    const int lane = threadIdx.x & 63;
    const int quad = lane >> 4;
    const int l16  = lane & 15;
    const int sw   = l16 & 7;
    const int m0 = blockIdx.x * 64;
    const int n0 = blockIdx.y * 64;

    const int lrow = lane >> 3;
    const int lchk = (lane & 7) ^ lrow;
    const int r0 = wave * 16;
    const __hip_bfloat16* ag0 = x + (size_t)(m0 + r0 + lrow) * E_ + lchk * 8;
    const __hip_bfloat16* ag1 = x + (size_t)(m0 + r0 + 8 + lrow) * E_ + lchk * 8;
    const __hip_bfloat16* bg0 = wfc_bf + (size_t)(n0 + r0 + lrow) * E_ + lchk * 8;
    const __hip_bfloat16* bg1 = wfc_bf + (size_t)(n0 + r0 + 8 + lrow) * E_ + lchk * 8;

    f4v acc[4];
    #pragma unroll
    for (int nt = 0; nt < 4; ++nt) acc[nt] = (f4v){0.f, 0.f, 0.f, 0.f};

    glds16(ag0, &abuf[0][r0 * 64]);
    glds16(ag1, &abuf[0][r0 * 64 + 512]);
    glds16(bg0, &bbuf[0][r0 * 64]);
    glds16(bg1, &bbuf[0][r0 * 64 + 512]);
    __syncthreads();

    int cur = 0;
    for (int it = 0; it < 16; ++it) {
        const int k0 = it * 64;
        if (it < 15) {
            glds16(ag0 + k0 + 64, &abuf[cur ^ 1][r0 * 64]);
            glds16(ag1 + k0 + 64, &abuf[cur ^ 1][r0 * 64 + 512]);
            glds16(bg0 + k0 + 64, &bbuf[cur ^ 1][r0 * 64]);
            glds16(bg1 + k0 + 64, &bbuf[cur ^ 1][r0 * 64 + 512]);
        }
        const ushort* ar = &abuf[cur][(r0 + l16) * 64];
        s8v a0 = *(const s8v*)(ar + ((quad ^ sw) << 3));
        s8v a1 = *(const s8v*)(ar + (((quad + 4) ^ sw) << 3));
        #pragma unroll
        for (int nt = 0; nt < 4; ++nt) {
            const ushort* br = &bbuf[cur][(nt * 16 + l16) * 64];
            s8v b0 = *(const s8v*)(br + ((quad ^ sw) << 3));
            s8v b1 = *(const s8v*)(br + (((quad + 4) ^ sw) << 3));
            acc[nt] = mfma16(a0, b0, acc[nt]);
            acc[nt] = mfma16(a1, b1, acc[nt]);
        }
        __syncthreads();
        cur ^= 1;
    }
    #pragma unroll
    for (int r = 0; r < 4; ++r) {
        const int m = m0 + r0 + quad * 4 + r;
        #pragma unroll
        for (int nt = 0; nt < 4; ++nt) {
            const int n = n0 + nt * 16 + l16;
            const float val = acc[nt][r] + __bfloat162float(bfc_bf[n]);
            if (isf32) ((float*)out)[(size_t)m * E_ + n] = val;
            else       ((__hip_bfloat16*)out)[(size_t)m * E_ + n] = __float2bfloat16(val);
        }
    }
}

extern "C" void kernel_launch(void* const* d_in, const int* in_sizes, int n_in,
                              void* d_out, int out_size, void* d_ws, size_t ws_size,
                              hipStream_t stream) {
    const void* query = d_in[0];
    const void* value = d_in[1];
    const void* key   = d_in[2];
    const int*  mask  = (const int*)d_in[3];
    const void* Wq  = d_in[4];
    const void* Wk  = d_in[5];
    const void* Wv  = d_in[6];
    const void* Wfc = d_in[7];
    const void* bfc = d_in[8];

    char* ws = (char*)d_ws;
    int* flag                     = (int*)ws;
    unsigned long long* mbits     = (unsigned long long*)(ws + (64u << 10));
    __hip_bfloat16* qp            = (__hip_bfloat16*)(ws + (2u  << 20));
    __hip_bfloat16* kp            = (__hip_bfloat16*)(ws + (10u << 20));
    __hip_bfloat16* vpT           = (__hip_bfloat16*)(ws + (18u << 20));
    __hip_bfloat16* attn_out      = (__hip_bfloat16*)(ws + (26u << 20));

    const bool big_ws = ws_size >= (37ull << 20);
    __hip_bfloat16* wfc_bf = big_ws ? (__hip_bfloat16*)(ws + (34ull << 20)) : qp;
    __hip_bfloat16* bfc_bf = wfc_bf + (size_t)E_ * E_;

    detect_kernel<<<1, 256, 0, stream>>>((const ushort*)query, flag);
    proj_all_kernel<<<dim3(1024, big_ws ? 5 : 4), 256, 0, stream>>>(
        query, key, value, Wq, Wk, Wv, Wfc, bfc, mask, mbits,
        qp, kp, vpT, wfc_bf, bfc_bf, flag);
    attn_kernel<<<dim3(32, 32), 256, 0, stream>>>(qp, kp, vpT, mbits, attn_out);
    if (!big_ws)
        cvt_wfc_kernel<<<1025, 256, 0, stream>>>(Wfc, bfc, wfc_bf, bfc_bf, flag);
    fc_kernel<<<dim3(64, 16), 256, 0, stream>>>(attn_out, wfc_bf, bfc_bf, d_out, flag);
}